// Round 3
// baseline (77.780 us; speedup 1.0000x reference)
//
#include <hip/hip_runtime.h>

#define H 64
#define W 64
#define NPIX 4096          // 64*64
#define GHH 240
#define GWW 240
#define CB 512             // total channels in data
#define CX 256             // x channels
#define NTAP 64

// ---------- helpers: bf16 pack/unpack (bf16 = truncated f32, RNE pack) ----------
static __device__ __forceinline__ unsigned pk_bf16(float a, float b) {
    unsigned ua = __float_as_uint(a);
    ua = (ua + 0x7fffu + ((ua >> 16) & 1u)) >> 16;          // bf16(a) in low 16
    unsigned ub = __float_as_uint(b);
    ub = (ub + 0x7fffu + ((ub >> 16) & 1u)) & 0xffff0000u;  // bf16(b) in high 16
    return ua | ub;
}
static __device__ __forceinline__ float lo_bf16(unsigned u) { return __uint_as_float(u << 16); }
static __device__ __forceinline__ float hi_bf16(unsigned u) { return __uint_as_float(u & 0xffff0000u); }

// ---------- kernel 1: per (b,pixel) 64-tap stencil -> ws ----------
// grid: 8 b x 16 = 128 blocks x 256 threads; one pixel per thread.
__global__ __launch_bounds__(256)
void stencil_kernel(const float* __restrict__ data, float2* __restrict__ st) {
    const int b   = blockIdx.x & 7;
    const int pg  = blockIdx.x >> 3;
    const int pix = pg * 256 + threadIdx.x;
    const int oy = pix >> 6, ox = pix & 63;

    const float*  xbase = data + (size_t)b * CB * NPIX;
    const float2* gaff  = (const float2*)(xbase + (size_t)256 * NPIX);
    const float2* gtps  = (const float2*)(xbase + (size_t)384 * NPIX);
    float2* stb = st + (size_t)b * NTAP * NPIX;

    const float fy  = ((float)oy / 63.0f) * 239.0f;
    const float fx  = ((float)ox / 63.0f) * 239.0f;
    const float fy0 = floorf(fy), fx0 = floorf(fx);
    const float wy1 = fy - fy0,  wx1 = fx - fx0;

#pragma unroll
    for (int t = 0; t < 4; ++t) {
        const int tty = t >> 1, ttx = t & 1;
        const float gyf = fy0 + (float)tty;
        const float gxf = fx0 + (float)ttx;
        float wt = (tty ? wy1 : 1.0f - wy1) * (ttx ? wx1 : 1.0f - wx1);
        if (gyf < 0.0f || gyf > 239.0f || gxf < 0.0f || gxf > 239.0f) wt = 0.0f;
        const int gyi = min(max((int)gyf, 0), GHH - 1);
        const int gxi = min(max((int)gxf, 0), GWW - 1);

        const float2 gt = gtps[gyi * GWW + gxi];
        const float sx  = (gt.x + 1.0f) * 0.5f * 239.0f;
        const float sy  = (gt.y + 1.0f) * 0.5f * 239.0f;
        const float sy0 = floorf(sy), sx0 = floorf(sx);
        const float wsy1 = sy - sy0,  wsx1 = sx - sx0;

#pragma unroll
        for (int s = 0; s < 4; ++s) {
            const int ssy = s >> 1, ssx = s & 1;
            const float ayf = sy0 + (float)ssy;
            const float axf = sx0 + (float)ssx;
            float ws = (ssy ? wsy1 : 1.0f - wsy1) * (ssx ? wsx1 : 1.0f - wsx1);
            if (ayf < 0.0f || ayf > 239.0f || axf < 0.0f || axf > 239.0f) ws = 0.0f;
            ws *= wt;
            const int ayi = min(max((int)ayf, 0), GHH - 1);
            const int axi = min(max((int)axf, 0), GWW - 1);

            const float2 ga = gaff[ayi * GWW + axi];
            const float qx  = (ga.x + 1.0f) * 0.5f * 63.0f;
            const float qy  = (ga.y + 1.0f) * 0.5f * 63.0f;
            const float qy0 = floorf(qy), qx0 = floorf(qx);
            const float wqy1 = qy - qy0,  wqx1 = qx - qx0;

#pragma unroll
            for (int r = 0; r < 4; ++r) {
                const int rry = r >> 1, rrx = r & 1;
                const float byf = qy0 + (float)rry;
                const float bxf = qx0 + (float)rrx;
                float wr = (rry ? wqy1 : 1.0f - wqy1) * (rrx ? wqx1 : 1.0f - wqx1);
                if (byf < 0.0f || byf > 63.0f || bxf < 0.0f || bxf > 63.0f) wr = 0.0f;
                wr *= ws;
                const int byi = min(max((int)byf, 0), H - 1);
                const int bxi = min(max((int)bxf, 0), W - 1);
                const int tix = t * 16 + s * 4 + r;
                stb[(size_t)tix * NPIX + pix] =
                    make_float2(wr, __uint_as_float((unsigned)(byi * W + bxi)));
            }
        }
    }
}

// ---------- kernel 2: gather-FMA over bf16-packed LDS ----------
// grid: 8 b x 32 cg = 256 blocks x 1024 threads. 8 channels/block in 64 KB LDS.
__global__ __launch_bounds__(1024)
void gather_kernel(const float* __restrict__ data, const float2* __restrict__ st,
                   float* __restrict__ out) {
    __shared__ uint4 xl[NPIX];   // 64 KB: pixel -> 8 channels packed bf16
    const int tid = threadIdx.x;
    const int b   = blockIdx.x & 7;    // XCD pinning heuristic
    const int cg  = blockIdx.x >> 3;
    const int c0  = cg * 8;

    const float* xbase = data + (size_t)b * CB * NPIX;
    const float* xc    = xbase + (size_t)c0 * NPIX;

    // stage: scalar coalesced loads, conflict-free b128 LDS writes (stride 16B)
#pragma unroll
    for (int k = 0; k < 4; ++k) {
        const int p = k * 1024 + tid;
        float v0 = xc[0 * NPIX + p], v1 = xc[1 * NPIX + p];
        float v2 = xc[2 * NPIX + p], v3 = xc[3 * NPIX + p];
        float v4 = xc[4 * NPIX + p], v5 = xc[5 * NPIX + p];
        float v6 = xc[6 * NPIX + p], v7 = xc[7 * NPIX + p];
        uint4 u;
        u.x = pk_bf16(v0, v1); u.y = pk_bf16(v2, v3);
        u.z = pk_bf16(v4, v5); u.w = pk_bf16(v6, v7);
        xl[p] = u;
    }
    __syncthreads();

    const float2* stb = st + (size_t)b * NTAP * NPIX;

    for (int pg = 0; pg < 4; ++pg) {
        const int pix = pg * 1024 + tid;
        float a0 = 0.f, a1 = 0.f, a2 = 0.f, a3 = 0.f;
        float a4 = 0.f, a5 = 0.f, a6 = 0.f, a7 = 0.f;

#pragma unroll 8
        for (int t = 0; t < NTAP; ++t) {
            const float2 s = stb[(size_t)t * NPIX + pix];
            const float w = s.x;
            const uint4 v = xl[__float_as_uint(s.y)];
            a0 = fmaf(w, lo_bf16(v.x), a0); a1 = fmaf(w, hi_bf16(v.x), a1);
            a2 = fmaf(w, lo_bf16(v.y), a2); a3 = fmaf(w, hi_bf16(v.y), a3);
            a4 = fmaf(w, lo_bf16(v.z), a4); a5 = fmaf(w, hi_bf16(v.z), a5);
            a6 = fmaf(w, lo_bf16(v.w), a6); a7 = fmaf(w, hi_bf16(v.w), a7);
        }

        // residual (full-precision x from global, L2-resident) + coalesced stores
        float* o = out + ((size_t)b * CX + c0) * NPIX + pix;
        o[0 * NPIX] = xc[0 * NPIX + pix] + a0;
        o[1 * NPIX] = xc[1 * NPIX + pix] + a1;
        o[2 * NPIX] = xc[2 * NPIX + pix] + a2;
        o[3 * NPIX] = xc[3 * NPIX + pix] + a3;
        o[4 * NPIX] = xc[4 * NPIX + pix] + a4;
        o[5 * NPIX] = xc[5 * NPIX + pix] + a5;
        o[6 * NPIX] = xc[6 * NPIX + pix] + a6;
        o[7 * NPIX] = xc[7 * NPIX + pix] + a7;
    }
}

// ---------- fallback (round-2 proven kernel) if ws too small ----------
__global__ __launch_bounds__(1024, 4)
void warp_resblock_mono(const float* __restrict__ data, float* __restrict__ out) {
    const int tid = threadIdx.x;
    const int b   = blockIdx.x & 7;
    const int cg  = blockIdx.x >> 3;
    const int c0  = cg * 8;

    const float*  xbase = data + (size_t)b * CB * NPIX;
    const float2* gaff  = (const float2*)(xbase + (size_t)256 * NPIX);
    const float2* gtps  = (const float2*)(xbase + (size_t)384 * NPIX);

    __shared__ float4 xa[NPIX];
    __shared__ float4 xb[NPIX];
    {
        const float4* xs = (const float4*)(xbase + (size_t)c0 * NPIX);
        float4 va[4], vb[4];
#pragma unroll
        for (int cc = 0; cc < 4; ++cc) va[cc] = xs[(size_t)cc * 1024 + tid];
#pragma unroll
        for (int cc = 0; cc < 4; ++cc) vb[cc] = xs[(size_t)(4 + cc) * 1024 + tid];
#pragma unroll
        for (int k = 0; k < 4; ++k) {
            const int pix = tid * 4 + k;
            xa[pix] = make_float4(((const float*)&va[0])[k], ((const float*)&va[1])[k],
                                  ((const float*)&va[2])[k], ((const float*)&va[3])[k]);
            xb[pix] = make_float4(((const float*)&vb[0])[k], ((const float*)&vb[1])[k],
                                  ((const float*)&vb[2])[k], ((const float*)&vb[3])[k]);
        }
    }
    __syncthreads();

    for (int pg = 0; pg < 4; ++pg) {
        const int pix = pg * 1024 + tid;
        const int oy = pix >> 6, ox = pix & 63;
        float a0 = 0.f, a1 = 0.f, a2 = 0.f, a3 = 0.f;
        float a4 = 0.f, a5 = 0.f, a6 = 0.f, a7 = 0.f;

        const float fy  = ((float)oy / 63.0f) * 239.0f;
        const float fx  = ((float)ox / 63.0f) * 239.0f;
        const float fy0 = floorf(fy), fx0 = floorf(fx);
        const float wy1 = fy - fy0,  wx1 = fx - fx0;

#pragma unroll
        for (int t = 0; t < 4; ++t) {
            const int tty = t >> 1, ttx = t & 1;
            const float gyf = fy0 + (float)tty;
            const float gxf = fx0 + (float)ttx;
            float wt = (tty ? wy1 : 1.0f - wy1) * (ttx ? wx1 : 1.0f - wx1);
            if (gyf < 0.0f || gyf > 239.0f || gxf < 0.0f || gxf > 239.0f) wt = 0.0f;
            const int gyi = min(max((int)gyf, 0), GHH - 1);
            const int gxi = min(max((int)gxf, 0), GWW - 1);
            const float2 gt = gtps[gyi * GWW + gxi];
            const float sx  = (gt.x + 1.0f) * 0.5f * 239.0f;
            const float sy  = (gt.y + 1.0f) * 0.5f * 239.0f;
            const float sy0 = floorf(sy), sx0 = floorf(sx);
            const float wsy1 = sy - sy0,  wsx1 = sx - sx0;
#pragma unroll
            for (int s = 0; s < 4; ++s) {
                const int ssy = s >> 1, ssx = s & 1;
                const float ayf = sy0 + (float)ssy;
                const float axf = sx0 + (float)ssx;
                float ws = (ssy ? wsy1 : 1.0f - wsy1) * (ssx ? wsx1 : 1.0f - wsx1);
                if (ayf < 0.0f || ayf > 239.0f || axf < 0.0f || axf > 239.0f) ws = 0.0f;
                ws *= wt;
                const int ayi = min(max((int)ayf, 0), GHH - 1);
                const int axi = min(max((int)axf, 0), GWW - 1);
                const float2 ga = gaff[ayi * GWW + axi];
                const float qx  = (ga.x + 1.0f) * 0.5f * 63.0f;
                const float qy  = (ga.y + 1.0f) * 0.5f * 63.0f;
                const float qy0 = floorf(qy), qx0 = floorf(qx);
                const float wqy1 = qy - qy0,  wqx1 = qx - qx0;
#pragma unroll
                for (int r = 0; r < 4; ++r) {
                    const int rry = r >> 1, rrx = r & 1;
                    const float byf = qy0 + (float)rry;
                    const float bxf = qx0 + (float)rrx;
                    float wr = (rry ? wqy1 : 1.0f - wqy1) * (rrx ? wqx1 : 1.0f - wqx1);
                    if (byf < 0.0f || byf > 63.0f || bxf < 0.0f || bxf > 63.0f) wr = 0.0f;
                    wr *= ws;
                    const int byi = min(max((int)byf, 0), H - 1);
                    const int bxi = min(max((int)bxf, 0), W - 1);
                    const int idx = byi * W + bxi;
                    const float4 pa = xa[idx];
                    const float4 pb = xb[idx];
                    a0 = fmaf(wr, pa.x, a0); a1 = fmaf(wr, pa.y, a1);
                    a2 = fmaf(wr, pa.z, a2); a3 = fmaf(wr, pa.w, a3);
                    a4 = fmaf(wr, pb.x, a4); a5 = fmaf(wr, pb.y, a5);
                    a6 = fmaf(wr, pb.z, a6); a7 = fmaf(wr, pb.w, a7);
                }
            }
        }
        const float4 ra = xa[pix];
        const float4 rb = xb[pix];
        float* o = out + ((size_t)b * CX + c0) * NPIX + pix;
        o[0 * NPIX] = ra.x + a0; o[1 * NPIX] = ra.y + a1;
        o[2 * NPIX] = ra.z + a2; o[3 * NPIX] = ra.w + a3;
        o[4 * NPIX] = rb.x + a4; o[5 * NPIX] = rb.y + a5;
        o[6 * NPIX] = rb.z + a6; o[7 * NPIX] = rb.w + a7;
    }
}

extern "C" void kernel_launch(void* const* d_in, const int* in_sizes, int n_in,
                              void* d_out, int out_size, void* d_ws, size_t ws_size,
                              hipStream_t stream) {
    (void)in_sizes; (void)n_in; (void)out_size;
    const float* data = (const float*)d_in[0];
    float* out = (float*)d_out;
    const size_t ws_needed = (size_t)8 * NTAP * NPIX * sizeof(float2);  // 16.78 MB

    if (ws_size >= ws_needed) {
        float2* st = (float2*)d_ws;
        hipLaunchKernelGGL(stencil_kernel, dim3(128), dim3(256), 0, stream, data, st);
        hipLaunchKernelGGL(gather_kernel, dim3(256), dim3(1024), 0, stream, data, st, out);
    } else {
        hipLaunchKernelGGL(warp_resblock_mono, dim3(256), dim3(1024), 0, stream, data, out);
    }
}

// Round 4
// 53.440 us; speedup vs baseline: 1.4555x; 1.4555x over previous
//
#include <hip/hip_runtime.h>

#define H 64
#define W 64
#define NPIX 4096          // 64*64
#define GHH 240
#define GWW 240
#define CB 512             // total channels in data
#define CX 256             // x channels
#define NTAP 64
#define NT4  16            // taps packed 4-per-uint4

// ---------- helpers: bf16 pack/unpack ----------
static __device__ __forceinline__ unsigned pk_bf16(float a, float b) {
    unsigned ua = __float_as_uint(a);
    ua = (ua + 0x7fffu + ((ua >> 16) & 1u)) >> 16;          // bf16(a) in low 16
    unsigned ub = __float_as_uint(b);
    ub = (ub + 0x7fffu + ((ub >> 16) & 1u)) & 0xffff0000u;  // bf16(b) in high 16
    return ua | ub;
}
static __device__ __forceinline__ float lo_bf16(unsigned u) { return __uint_as_float(u << 16); }
static __device__ __forceinline__ float hi_bf16(unsigned u) { return __uint_as_float(u & 0xffff0000u); }
// weight packed in HIGH 16 bits (float-ready via one AND), idx in low 16
static __device__ __forceinline__ unsigned pk_wi(float w, unsigned idx) {
    unsigned ub = __float_as_uint(w);
    ub = (ub + 0x7fffu + ((ub >> 16) & 1u)) & 0xffff0000u;
    return ub | idx;
}

// ---------- kernel 1: per (b,pixel) 64-tap packed stencil -> ws ----------
// grid: 512 blocks x 64 threads; one pixel per thread. st4[b][g=0..15][pix].
__global__ __launch_bounds__(64)
void stencil_kernel(const float* __restrict__ data, uint4* __restrict__ st) {
    const int gid = blockIdx.x * 64 + threadIdx.x;   // 0..32767
    const int b   = gid & 7;
    const int pix = gid >> 3;
    const int oy = pix >> 6, ox = pix & 63;

    const float*  xbase = data + (size_t)b * CB * NPIX;
    const float2* gaff  = (const float2*)(xbase + (size_t)256 * NPIX);
    const float2* gtps  = (const float2*)(xbase + (size_t)384 * NPIX);
    uint4* stb = st + (size_t)b * NT4 * NPIX;

    const float fy  = ((float)oy / 63.0f) * 239.0f;
    const float fx  = ((float)ox / 63.0f) * 239.0f;
    const float fy0 = floorf(fy), fx0 = floorf(fx);
    const float wy1 = fy - fy0,  wx1 = fx - fx0;

#pragma unroll
    for (int t = 0; t < 4; ++t) {
        const int tty = t >> 1, ttx = t & 1;
        const float gyf = fy0 + (float)tty;
        const float gxf = fx0 + (float)ttx;
        float wt = (tty ? wy1 : 1.0f - wy1) * (ttx ? wx1 : 1.0f - wx1);
        if (gyf < 0.0f || gyf > 239.0f || gxf < 0.0f || gxf > 239.0f) wt = 0.0f;
        const int gyi = min(max((int)gyf, 0), GHH - 1);
        const int gxi = min(max((int)gxf, 0), GWW - 1);

        const float2 gt = gtps[gyi * GWW + gxi];
        const float sx  = (gt.x + 1.0f) * 0.5f * 239.0f;
        const float sy  = (gt.y + 1.0f) * 0.5f * 239.0f;
        const float sy0 = floorf(sy), sx0 = floorf(sx);
        const float wsy1 = sy - sy0,  wsx1 = sx - sx0;

#pragma unroll
        for (int s = 0; s < 4; ++s) {
            const int ssy = s >> 1, ssx = s & 1;
            const float ayf = sy0 + (float)ssy;
            const float axf = sx0 + (float)ssx;
            float ws = (ssy ? wsy1 : 1.0f - wsy1) * (ssx ? wsx1 : 1.0f - wsx1);
            if (ayf < 0.0f || ayf > 239.0f || axf < 0.0f || axf > 239.0f) ws = 0.0f;
            ws *= wt;
            const int ayi = min(max((int)ayf, 0), GHH - 1);
            const int axi = min(max((int)axf, 0), GWW - 1);

            const float2 ga = gaff[ayi * GWW + axi];
            const float qx  = (ga.x + 1.0f) * 0.5f * 63.0f;
            const float qy  = (ga.y + 1.0f) * 0.5f * 63.0f;
            const float qy0 = floorf(qy), qx0 = floorf(qx);
            const float wqy1 = qy - qy0,  wqx1 = qx - qx0;

            unsigned pk[4];
#pragma unroll
            for (int r = 0; r < 4; ++r) {
                const int rry = r >> 1, rrx = r & 1;
                const float byf = qy0 + (float)rry;
                const float bxf = qx0 + (float)rrx;
                float wr = (rry ? wqy1 : 1.0f - wqy1) * (rrx ? wqx1 : 1.0f - wqx1);
                if (byf < 0.0f || byf > 63.0f || bxf < 0.0f || bxf > 63.0f) wr = 0.0f;
                wr *= ws;
                const int byi = min(max((int)byf, 0), H - 1);
                const int bxi = min(max((int)bxf, 0), W - 1);
                pk[r] = pk_wi(wr, (unsigned)(byi * W + bxi));
            }
            stb[(size_t)(t * 4 + s) * NPIX + pix] = make_uint4(pk[0], pk[1], pk[2], pk[3]);
        }
    }
}

// ---------- kernel 2: gather-FMA over bf16-packed LDS ----------
// grid: 8 b x 32 cg x 2 halves = 512 blocks x 1024 threads; 64 KB LDS each
// -> 2 blocks/CU, 32 waves/CU.
__global__ __launch_bounds__(1024)
void gather_kernel(const float* __restrict__ data, const uint4* __restrict__ st,
                   float* __restrict__ out) {
    __shared__ uint4 xl[NPIX];   // 64 KB: pixel -> 8 channels packed bf16
    const int tid  = threadIdx.x;
    const int b    = blockIdx.x & 7;        // XCD pinning heuristic
    const int cg   = (blockIdx.x >> 3) & 31;
    const int half = blockIdx.x >> 8;       // 0/1: pixel half
    const int c0   = cg * 8;

    const float* xbase = data + (size_t)b * CB * NPIX;
    const float* xc    = xbase + (size_t)c0 * NPIX;

    // stage full 8-channel image (both halves need all source pixels)
#pragma unroll
    for (int k = 0; k < 4; ++k) {
        const int p = k * 1024 + tid;
        float v0 = xc[0 * NPIX + p], v1 = xc[1 * NPIX + p];
        float v2 = xc[2 * NPIX + p], v3 = xc[3 * NPIX + p];
        float v4 = xc[4 * NPIX + p], v5 = xc[5 * NPIX + p];
        float v6 = xc[6 * NPIX + p], v7 = xc[7 * NPIX + p];
        uint4 u;
        u.x = pk_bf16(v0, v1); u.y = pk_bf16(v2, v3);
        u.z = pk_bf16(v4, v5); u.w = pk_bf16(v6, v7);
        xl[p] = u;
    }
    __syncthreads();

    const uint4* stb = st + (size_t)b * NT4 * NPIX;

#pragma unroll
    for (int pg = 0; pg < 2; ++pg) {
        const int pix = half * 2048 + pg * 1024 + tid;
        float a0 = 0.f, a1 = 0.f, a2 = 0.f, a3 = 0.f;
        float a4 = 0.f, a5 = 0.f, a6 = 0.f, a7 = 0.f;

#pragma unroll 4
        for (int g = 0; g < NT4; ++g) {
            const uint4 s4 = stb[(size_t)g * NPIX + pix];
#pragma unroll
            for (int r = 0; r < 4; ++r) {
                const unsigned u = (&s4.x)[r];
                const float w = __uint_as_float(u & 0xffff0000u);
                const uint4 v = xl[u & 0xffffu];
                a0 = fmaf(w, lo_bf16(v.x), a0); a1 = fmaf(w, hi_bf16(v.x), a1);
                a2 = fmaf(w, lo_bf16(v.y), a2); a3 = fmaf(w, hi_bf16(v.y), a3);
                a4 = fmaf(w, lo_bf16(v.z), a4); a5 = fmaf(w, hi_bf16(v.z), a5);
                a6 = fmaf(w, lo_bf16(v.w), a6); a7 = fmaf(w, hi_bf16(v.w), a7);
            }
        }

        // residual (full-precision x from global, L2-resident) + coalesced stores
        float* o = out + ((size_t)b * CX + c0) * NPIX + pix;
        o[0 * NPIX] = xc[0 * NPIX + pix] + a0;
        o[1 * NPIX] = xc[1 * NPIX + pix] + a1;
        o[2 * NPIX] = xc[2 * NPIX + pix] + a2;
        o[3 * NPIX] = xc[3 * NPIX + pix] + a3;
        o[4 * NPIX] = xc[4 * NPIX + pix] + a4;
        o[5 * NPIX] = xc[5 * NPIX + pix] + a5;
        o[6 * NPIX] = xc[6 * NPIX + pix] + a6;
        o[7 * NPIX] = xc[7 * NPIX + pix] + a7;
    }
}

// ---------- fallback (round-2 proven kernel) if ws too small ----------
__global__ __launch_bounds__(1024, 4)
void warp_resblock_mono(const float* __restrict__ data, float* __restrict__ out) {
    const int tid = threadIdx.x;
    const int b   = blockIdx.x & 7;
    const int cg  = blockIdx.x >> 3;
    const int c0  = cg * 8;

    const float*  xbase = data + (size_t)b * CB * NPIX;
    const float2* gaff  = (const float2*)(xbase + (size_t)256 * NPIX);
    const float2* gtps  = (const float2*)(xbase + (size_t)384 * NPIX);

    __shared__ float4 xa[NPIX];
    __shared__ float4 xb[NPIX];
    {
        const float4* xs = (const float4*)(xbase + (size_t)c0 * NPIX);
        float4 va[4], vb[4];
#pragma unroll
        for (int cc = 0; cc < 4; ++cc) va[cc] = xs[(size_t)cc * 1024 + tid];
#pragma unroll
        for (int cc = 0; cc < 4; ++cc) vb[cc] = xs[(size_t)(4 + cc) * 1024 + tid];
#pragma unroll
        for (int k = 0; k < 4; ++k) {
            const int pix = tid * 4 + k;
            xa[pix] = make_float4(((const float*)&va[0])[k], ((const float*)&va[1])[k],
                                  ((const float*)&va[2])[k], ((const float*)&va[3])[k]);
            xb[pix] = make_float4(((const float*)&vb[0])[k], ((const float*)&vb[1])[k],
                                  ((const float*)&vb[2])[k], ((const float*)&vb[3])[k]);
        }
    }
    __syncthreads();

    for (int pg = 0; pg < 4; ++pg) {
        const int pix = pg * 1024 + tid;
        const int oy = pix >> 6, ox = pix & 63;
        float a0 = 0.f, a1 = 0.f, a2 = 0.f, a3 = 0.f;
        float a4 = 0.f, a5 = 0.f, a6 = 0.f, a7 = 0.f;

        const float fy  = ((float)oy / 63.0f) * 239.0f;
        const float fx  = ((float)ox / 63.0f) * 239.0f;
        const float fy0 = floorf(fy), fx0 = floorf(fx);
        const float wy1 = fy - fy0,  wx1 = fx - fx0;

#pragma unroll
        for (int t = 0; t < 4; ++t) {
            const int tty = t >> 1, ttx = t & 1;
            const float gyf = fy0 + (float)tty;
            const float gxf = fx0 + (float)ttx;
            float wt = (tty ? wy1 : 1.0f - wy1) * (ttx ? wx1 : 1.0f - wx1);
            if (gyf < 0.0f || gyf > 239.0f || gxf < 0.0f || gxf > 239.0f) wt = 0.0f;
            const int gyi = min(max((int)gyf, 0), GHH - 1);
            const int gxi = min(max((int)gxf, 0), GWW - 1);
            const float2 gt = gtps[gyi * GWW + gxi];
            const float sx  = (gt.x + 1.0f) * 0.5f * 239.0f;
            const float sy  = (gt.y + 1.0f) * 0.5f * 239.0f;
            const float sy0 = floorf(sy), sx0 = floorf(sx);
            const float wsy1 = sy - sy0,  wsx1 = sx - sx0;
#pragma unroll
            for (int s = 0; s < 4; ++s) {
                const int ssy = s >> 1, ssx = s & 1;
                const float ayf = sy0 + (float)ssy;
                const float axf = sx0 + (float)ssx;
                float ws = (ssy ? wsy1 : 1.0f - wsy1) * (ssx ? wsx1 : 1.0f - wsx1);
                if (ayf < 0.0f || ayf > 239.0f || axf < 0.0f || axf > 239.0f) ws = 0.0f;
                ws *= wt;
                const int ayi = min(max((int)ayf, 0), GHH - 1);
                const int axi = min(max((int)axf, 0), GWW - 1);
                const float2 ga = gaff[ayi * GWW + axi];
                const float qx  = (ga.x + 1.0f) * 0.5f * 63.0f;
                const float qy  = (ga.y + 1.0f) * 0.5f * 63.0f;
                const float qy0 = floorf(qy), qx0 = floorf(qx);
                const float wqy1 = qy - qy0,  wqx1 = qx - qx0;
#pragma unroll
                for (int r = 0; r < 4; ++r) {
                    const int rry = r >> 1, rrx = r & 1;
                    const float byf = qy0 + (float)rry;
                    const float bxf = qx0 + (float)rrx;
                    float wr = (rry ? wqy1 : 1.0f - wqy1) * (rrx ? wqx1 : 1.0f - wqx1);
                    if (byf < 0.0f || byf > 63.0f || bxf < 0.0f || bxf > 63.0f) wr = 0.0f;
                    wr *= ws;
                    const int byi = min(max((int)byf, 0), H - 1);
                    const int bxi = min(max((int)bxf, 0), W - 1);
                    const int idx = byi * W + bxi;
                    const float4 pa = xa[idx];
                    const float4 pb = xb[idx];
                    a0 = fmaf(wr, pa.x, a0); a1 = fmaf(wr, pa.y, a1);
                    a2 = fmaf(wr, pa.z, a2); a3 = fmaf(wr, pa.w, a3);
                    a4 = fmaf(wr, pb.x, a4); a5 = fmaf(wr, pb.y, a5);
                    a6 = fmaf(wr, pb.z, a6); a7 = fmaf(wr, pb.w, a7);
                }
            }
        }
        const float4 ra = xa[pix];
        const float4 rb = xb[pix];
        float* o = out + ((size_t)b * CX + c0) * NPIX + pix;
        o[0 * NPIX] = ra.x + a0; o[1 * NPIX] = ra.y + a1;
        o[2 * NPIX] = ra.z + a2; o[3 * NPIX] = ra.w + a3;
        o[4 * NPIX] = rb.x + a4; o[5 * NPIX] = rb.y + a5;
        o[6 * NPIX] = rb.z + a6; o[7 * NPIX] = rb.w + a7;
    }
}

extern "C" void kernel_launch(void* const* d_in, const int* in_sizes, int n_in,
                              void* d_out, int out_size, void* d_ws, size_t ws_size,
                              hipStream_t stream) {
    (void)in_sizes; (void)n_in; (void)out_size;
    const float* data = (const float*)d_in[0];
    float* out = (float*)d_out;
    const size_t ws_needed = (size_t)8 * NT4 * NPIX * sizeof(uint4);  // 8.39 MB

    if (ws_size >= ws_needed) {
        uint4* st = (uint4*)d_ws;
        hipLaunchKernelGGL(stencil_kernel, dim3(512), dim3(64), 0, stream, data, st);
        hipLaunchKernelGGL(gather_kernel, dim3(512), dim3(1024), 0, stream, data, st, out);
    } else {
        hipLaunchKernelGGL(warp_resblock_mono, dim3(256), dim3(1024), 0, stream, data, out);
    }
}